// Round 5
// baseline (842.774 us; speedup 1.0000x reference)
//
#include <hip/hip_runtime.h>
#include <hip/hip_bf16.h>
#include <math.h>

#define DIM 896
#define DD  (DIM * DIM)
#define NH 8
#define HD 112
#define BB 64
#define TT 8
#define KA 65
#define KAPAD 4224   // 64*65 = 4160 padded to 33*128
#define KT 512
#define NKEYS (TT + KA + KT)   // 585
#define NCH 4                  // attention key chunks
#define PSTRIDE 912            // per (bh,chunk) partial: 896 O + 8 m + 8 l (floats)

#define EPI_NONE  0
#define EPI_ROPE  1
#define EPI_RESID 2
#define EPI_RELU  3

// -log2(10000)/56
#define NEG_L2_10K_OVER_56 (-0.2373327285062406f)

#ifndef __has_builtin
#define __has_builtin(x) 0
#endif
#if __has_builtin(__builtin_amdgcn_global_load_lds)
#define HAS_GLL 1
#else
#define HAS_GLL 0
#endif

typedef __attribute__((ext_vector_type(8))) short bf16x8_t;
typedef __attribute__((ext_vector_type(4))) float f32x4_t;

__device__ __forceinline__ short f2bf(float f) {  // RNE
  unsigned u = __float_as_uint(f);
  u += 0x7fffu + ((u >> 16) & 1u);
  return (short)(u >> 16);
}
__device__ __forceinline__ float bf2f(short s) {
  return __uint_as_float(((unsigned)(unsigned short)s) << 16);
}
// pack hi16(f1):hi16(f0) -> one u32 (used with +0x8000 pre-round)
__device__ __forceinline__ unsigned pack_bf2(unsigned u0, unsigned u1) {
  return __builtin_amdgcn_perm(u1, u0, 0x07060302u);
}

// ---------------- 9-way weight transpose: W[k][n] f32 -> Wt[n][k] bf16 ----------------
struct W9 { const float* w[9]; };

__global__ __launch_bounds__(256) void wtrans(W9 ws, short* __restrict__ Wt)
{
  __shared__ float t[32][33];
  const float* W = ws.w[blockIdx.z];
  short* dst = Wt + (size_t)blockIdx.z * DD;
  const int bx = blockIdx.x, by = blockIdx.y;
  const int tx = threadIdx.x & 31, ty = threadIdx.x >> 5;
#pragma unroll
  for (int i = 0; i < 4; ++i)
    t[ty + i * 8][tx] = W[(size_t)(by * 32 + ty + i * 8) * DIM + bx * 32 + tx];
  __syncthreads();
#pragma unroll
  for (int i = 0; i < 4; ++i)
    dst[(size_t)(bx * 32 + ty + i * 8) * DIM + by * 32 + tx] = f2bf(t[tx][ty + i * 8]);
}

// ---------------- fp32 -> bf16 elementwise ----------------
__global__ __launch_bounds__(256) void convert_bf16(
    const float* __restrict__ src, short* __restrict__ dst, int n8)
{
  const int i = blockIdx.x * 256 + threadIdx.x;
  if (i >= n8) return;
  const float4 a = ((const float4*)src)[i * 2];
  const float4 b = ((const float4*)src)[i * 2 + 1];
  bf16x8_t o;
  o[0] = f2bf(a.x); o[1] = f2bf(a.y); o[2] = f2bf(a.z); o[3] = f2bf(a.w);
  o[4] = f2bf(b.x); o[5] = f2bf(b.y); o[6] = f2bf(b.z); o[7] = f2bf(b.w);
  ((bf16x8_t*)dst)[i] = o;
}

// ---------------- h_ad = concat(h_a, p) -> bf16, zero-padded to 4224 rows ----------------
__global__ __launch_bounds__(256) void build_had(
    const float* __restrict__ h_a, const float* __restrict__ p,
    short* __restrict__ had)
{
  const int i = blockIdx.x * 256 + threadIdx.x;
  const int total = KAPAD * DIM / 8;
  if (i >= total) return;
  const int c = (i % 112) * 8;
  const int row = i / 112;
  bf16x8_t o;
  if (row >= BB * KA) {
#pragma unroll
    for (int j = 0; j < 8; ++j) o[j] = 0;
  } else {
    const int b = row / KA, j = row % KA;
    const float* src = (j < KA - 1) ? h_a + ((size_t)b * (KA - 1) + j) * DIM + c
                                    : p + (size_t)b * DIM + c;
    const float4 a = *(const float4*)src;
    const float4 d = *(const float4*)(src + 4);
    o[0] = f2bf(a.x); o[1] = f2bf(a.y); o[2] = f2bf(a.z); o[3] = f2bf(a.w);
    o[4] = f2bf(d.x); o[5] = f2bf(d.y); o[6] = f2bf(d.z); o[7] = f2bf(d.w);
  }
  ((bf16x8_t*)had)[i] = o;
}

// ---------------- shared epilogue ----------------
struct EpiCfg {
  const float* bias[3];
  float* outF[3];
  short* outB[3];
  const float* resid;
  int epi[3];
  int pos_mod[3];
};

__device__ __forceinline__ void gemm_epilogue(
    const EpiCfg& cfg, int sub, const f32x4_t acc[4][4],
    int row0, int col0, int wm, int wn, int lm, int lq)
{
  const float* bias = cfg.bias[sub];
  float* outF = cfg.outF[sub];
  short* outB = cfg.outB[sub];
  const int epi = cfg.epi[sub], pm = cfg.pos_mod[sub];
#pragma unroll
  for (int tn = 0; tn < 4; ++tn) {
    const int col = col0 + wn * 64 + tn * 16 + lm;
    const float bv = bias[col];
    float fr = 0.f, sgn = 0.f;
    if (epi == EPI_ROPE) {
      const int d0 = col % HD;
      fr = exp2f((float)(d0 % 56) * NEG_L2_10K_OVER_56);
      sgn = (d0 & 1) ? 1.f : -1.f;
    }
#pragma unroll
    for (int tm = 0; tm < 4; ++tm) {
#pragma unroll
      for (int r = 0; r < 4; ++r) {
        const int grow = row0 + wm * 64 + tm * 16 + lq * 4 + r;
        float v = acc[tm][tn][r] + bv;
        if (epi == EPI_ROPE) {
          const float prt = __shfl_xor(v, 1);
          float s, c;
          __sincosf((float)(grow % pm) * fr, &s, &c);
          v = v * c + sgn * prt * s;
        } else if (epi == EPI_RESID) {
          v += cfg.resid[(size_t)grow * DIM + col];
        } else if (epi == EPI_RELU) {
          v = fmaxf(v, 0.f);
        }
        if (outB) outB[(size_t)grow * DIM + col] = f2bf(v);
        else      outF[(size_t)grow * DIM + col] = v;
      }
    }
  }
}

// ---------------- MFMA GEMM, bf16 A (m97 structure) ----------------
__global__ __launch_bounds__(256) void gemm_bf16(
    const short* __restrict__ A, const short* __restrict__ Wt, EpiCfg cfg)
{
  __shared__ __align__(16) short As[128 * 32];
  __shared__ __align__(16) short Bs[128 * 32];
  const int tid = threadIdx.x;
  const int wave = tid >> 6, lane = tid & 63;
  const int sub = blockIdx.x / 7;
  const int col0 = (blockIdx.x % 7) * 128;
  const int row0 = blockIdx.y * 128;
  const int wm = wave >> 1, wn = wave & 1;
  const int lm = lane & 15, lq = lane >> 4;

  const int sm = lane >> 2, sk = (lane & 3) * 8;
  const short* Ag0 = A + (size_t)(row0 + wave * 32 + sm) * DIM + sk;
  const short* Ag1 = Ag0 + (size_t)16 * DIM;
  const short* Wg0 = Wt + (size_t)(sub * DIM + col0 + wave * 32 + sm) * DIM + sk;
  const short* Wg1 = Wg0 + (size_t)16 * DIM;

  f32x4_t acc[4][4];
#pragma unroll
  for (int i = 0; i < 4; ++i)
#pragma unroll
    for (int j = 0; j < 4; ++j) acc[i][j] = (f32x4_t){0.f, 0.f, 0.f, 0.f};

  for (int k0 = 0; k0 < DIM; k0 += 32) {
    __syncthreads();
#if HAS_GLL
    __builtin_amdgcn_global_load_lds(
        (const __attribute__((address_space(1))) unsigned*)(Ag0 + k0),
        (__attribute__((address_space(3))) unsigned*)&As[(wave * 32) * 32], 16, 0, 0);
    __builtin_amdgcn_global_load_lds(
        (const __attribute__((address_space(1))) unsigned*)(Ag1 + k0),
        (__attribute__((address_space(3))) unsigned*)&As[(wave * 32 + 16) * 32], 16, 0, 0);
    __builtin_amdgcn_global_load_lds(
        (const __attribute__((address_space(1))) unsigned*)(Wg0 + k0),
        (__attribute__((address_space(3))) unsigned*)&Bs[(wave * 32) * 32], 16, 0, 0);
    __builtin_amdgcn_global_load_lds(
        (const __attribute__((address_space(1))) unsigned*)(Wg1 + k0),
        (__attribute__((address_space(3))) unsigned*)&Bs[(wave * 32 + 16) * 32], 16, 0, 0);
#else
    {
      const int m = tid >> 1, kh = (tid & 1) * 16;
      *(bf16x8_t*)&As[m * 32 + kh] =
          *(const bf16x8_t*)(A + (size_t)(row0 + m) * DIM + k0 + kh);
      *(bf16x8_t*)&As[m * 32 + kh + 8] =
          *(const bf16x8_t*)(A + (size_t)(row0 + m) * DIM + k0 + kh + 8);
      *(bf16x8_t*)&Bs[m * 32 + kh] =
          *(const bf16x8_t*)(Wt + (size_t)(sub * DIM + col0 + m) * DIM + k0 + kh);
      *(bf16x8_t*)&Bs[m * 32 + kh + 8] =
          *(const bf16x8_t*)(Wt + (size_t)(sub * DIM + col0 + m) * DIM + k0 + kh + 8);
    }
#endif
    __syncthreads();

    bf16x8_t af[4], bfr[4];
#pragma unroll
    for (int t = 0; t < 4; ++t)
      af[t] = *(const bf16x8_t*)&As[(wm * 64 + t * 16 + lm) * 32 + lq * 8];
#pragma unroll
    for (int t = 0; t < 4; ++t)
      bfr[t] = *(const bf16x8_t*)&Bs[(wn * 64 + t * 16 + lm) * 32 + lq * 8];
#pragma unroll
    for (int tm = 0; tm < 4; ++tm)
#pragma unroll
      for (int tn = 0; tn < 4; ++tn)
        acc[tm][tn] = __builtin_amdgcn_mfma_f32_16x16x32_bf16(
            af[tm], bfr[tn], acc[tm][tn], 0, 0, 0);
  }
  gemm_epilogue(cfg, sub, acc, row0, col0, wm, wn, lm, lq);
}

// ---------------- MFMA GEMM, fp32 A staged via gll, cvt after ds_read ----------------
__global__ __launch_bounds__(256) void gemm_f32a(
    const float* __restrict__ A, const short* __restrict__ Wt, EpiCfg cfg)
{
  __shared__ __align__(16) float Asf[128 * 32];   // 16 KB, [m][k] 128-B rows
  __shared__ __align__(16) short Bs[128 * 32];    // 8 KB
  const int tid = threadIdx.x;
  const int wave = tid >> 6, lane = tid & 63;
  const int sub = blockIdx.x / 7;
  const int col0 = (blockIdx.x % 7) * 128;
  const int row0 = blockIdx.y * 128;
  const int wm = wave >> 1, wn = wave & 1;
  const int lm = lane & 15, lq = lane >> 4;

  // A: lane -> row (lane>>3), col floats (lane&7)*4; 4 gll x 8 rows per wave
  const float* Ag = A + (size_t)(row0 + wave * 32 + (lane >> 3)) * DIM + (lane & 7) * 4;
  // B: as in gemm_bf16
  const int sm = lane >> 2, sk = (lane & 3) * 8;
  const short* Wg0 = Wt + (size_t)(sub * DIM + col0 + wave * 32 + sm) * DIM + sk;
  const short* Wg1 = Wg0 + (size_t)16 * DIM;

  f32x4_t acc[4][4];
#pragma unroll
  for (int i = 0; i < 4; ++i)
#pragma unroll
    for (int j = 0; j < 4; ++j) acc[i][j] = (f32x4_t){0.f, 0.f, 0.f, 0.f};

  for (int k0 = 0; k0 < DIM; k0 += 32) {
    __syncthreads();
#if HAS_GLL
#pragma unroll
    for (int i = 0; i < 4; ++i)
      __builtin_amdgcn_global_load_lds(
          (const __attribute__((address_space(1))) unsigned*)(Ag + (size_t)(i * 8) * DIM + k0),
          (__attribute__((address_space(3))) unsigned*)&Asf[(wave * 32 + i * 8) * 32], 16, 0, 0);
    __builtin_amdgcn_global_load_lds(
        (const __attribute__((address_space(1))) unsigned*)(Wg0 + k0),
        (__attribute__((address_space(3))) unsigned*)&Bs[(wave * 32) * 32], 16, 0, 0);
    __builtin_amdgcn_global_load_lds(
        (const __attribute__((address_space(1))) unsigned*)(Wg1 + k0),
        (__attribute__((address_space(3))) unsigned*)&Bs[(wave * 32 + 16) * 32], 16, 0, 0);
#else
    {
      const int m = tid >> 1, kh = (tid & 1) * 16;
      *(float4*)&Asf[m * 32 + kh] = *(const float4*)(A + (size_t)(row0 + m) * DIM + k0 + kh);
      *(float4*)&Asf[m * 32 + kh + 4] = *(const float4*)(A + (size_t)(row0 + m) * DIM + k0 + kh + 4);
      *(float4*)&Asf[m * 32 + kh + 8] = *(const float4*)(A + (size_t)(row0 + m) * DIM + k0 + kh + 8);
      *(float4*)&Asf[m * 32 + kh + 12] = *(const float4*)(A + (size_t)(row0 + m) * DIM + k0 + kh + 12);
      *(bf16x8_t*)&Bs[m * 32 + kh] =
          *(const bf16x8_t*)(Wt + (size_t)(sub * DIM + col0 + m) * DIM + k0 + kh);
      *(bf16x8_t*)&Bs[m * 32 + kh + 8] =
          *(const bf16x8_t*)(Wt + (size_t)(sub * DIM + col0 + m) * DIM + k0 + kh + 8);
    }
#endif
    __syncthreads();

    bf16x8_t af[4], bfr[4];
#pragma unroll
    for (int t = 0; t < 4; ++t) {
      const float* ap = &Asf[(wm * 64 + t * 16 + lm) * 32 + lq * 8];
      const float4 f0 = *(const float4*)ap;
      const float4 f1 = *(const float4*)(ap + 4);
      // round-half-up to bf16 (+0x8000 then take hi16), packed via v_perm
      unsigned p0 = pack_bf2(__float_as_uint(f0.x) + 0x8000u, __float_as_uint(f0.y) + 0x8000u);
      unsigned p1 = pack_bf2(__float_as_uint(f0.z) + 0x8000u, __float_as_uint(f0.w) + 0x8000u);
      unsigned p2 = pack_bf2(__float_as_uint(f1.x) + 0x8000u, __float_as_uint(f1.y) + 0x8000u);
      unsigned p3 = pack_bf2(__float_as_uint(f1.z) + 0x8000u, __float_as_uint(f1.w) + 0x8000u);
      af[t][0] = (short)(p0 & 0xffff); af[t][1] = (short)(p0 >> 16);
      af[t][2] = (short)(p1 & 0xffff); af[t][3] = (short)(p1 >> 16);
      af[t][4] = (short)(p2 & 0xffff); af[t][5] = (short)(p2 >> 16);
      af[t][6] = (short)(p3 & 0xffff); af[t][7] = (short)(p3 >> 16);
    }
#pragma unroll
    for (int t = 0; t < 4; ++t)
      bfr[t] = *(const bf16x8_t*)&Bs[(wn * 64 + t * 16 + lm) * 32 + lq * 8];
#pragma unroll
    for (int tm = 0; tm < 4; ++tm)
#pragma unroll
      for (int tn = 0; tn < 4; ++tn)
        acc[tm][tn] = __builtin_amdgcn_mfma_f32_16x16x32_bf16(
            af[tm], bfr[tn], acc[tm][tn], 0, 0, 0);
  }
  gemm_epilogue(cfg, sub, acc, row0, col0, wm, wn, lm, lq);
}

// ---------------- attention, split-K partials ----------------
// grid (512, NCH). chunk 0: 73 self+ad keys; chunks 1..3: 171/171/170 task keys.
__global__ __launch_bounds__(256) void attn_part(
    const short* __restrict__ q, const short* __restrict__ k_s,
    const short* __restrict__ k_a, const short* __restrict__ k_t,
    const short* __restrict__ v_s, const short* __restrict__ v_a,
    const short* __restrict__ v_t, const float* __restrict__ gate,
    float* __restrict__ part)
{
  __shared__ float qs[HD][TT];
  __shared__ float sc[TT][176];
  __shared__ float msh[TT], lsh[TT];
  const int tid = threadIdx.x;
  const int bh = blockIdx.x, b = bh >> 3, h = bh & 7;
  const int ch = blockIdx.y;
  const float scale = 0.09449111825230681f;  // 1/sqrt(112)
  const int nk = (ch == 0) ? (TT + KA) : ((ch == 3) ? 170 : 171);
  const int t0 = (ch >= 1) ? (ch - 1) * 171 : 0;   // task-key base

  for (int idx = tid; idx < TT * HD; idx += 256) {
    const int t = idx / HD, d = idx % HD;
    qs[d][t] = bf2f(q[(size_t)(b * TT + t) * DIM + h * HD + d]);
  }
  __syncthreads();

  // scores: thread-per-key
  if (tid < nk) {
    const short* kp;
    float s = scale;
    if (ch == 0) {
      kp = (tid < TT) ? k_s + (size_t)(b * TT + tid) * DIM + h * HD
                      : k_a + (size_t)(b * KA + (tid - TT)) * DIM + h * HD;
    } else {
      kp = k_t + (size_t)(b * KT + t0 + tid) * DIM + h * HD;
      s = scale * tanhf(gate[0]);
    }
    float dot[TT] = {};
    for (int d8 = 0; d8 < HD; d8 += 8) {
      const bf16x8_t kv8 = *(const bf16x8_t*)(kp + d8);
#pragma unroll
      for (int j = 0; j < 8; ++j) {
        const float kv = bf2f(kv8[j]);
#pragma unroll
        for (int t = 0; t < TT; ++t) dot[t] = fmaf(qs[d8 + j][t], kv, dot[t]);
      }
    }
#pragma unroll
    for (int t = 0; t < TT; ++t) sc[t][tid] = dot[t] * s;
  }
  __syncthreads();

  // local softmax per t (wave w: t = w, w+4)
  const int wave = tid >> 6, lane = tid & 63;
  for (int t = wave; t < TT; t += 4) {
    float m = -1e30f;
    for (int k = lane; k < nk; k += 64) m = fmaxf(m, sc[t][k]);
#pragma unroll
    for (int o = 32; o >= 1; o >>= 1) m = fmaxf(m, __shfl_xor(m, o));
    float sum = 0.f;
    for (int k = lane; k < nk; k += 64) {
      const float e = expf(sc[t][k] - m);
      sc[t][k] = e;
      sum += e;
    }
#pragma unroll
    for (int o = 32; o >= 1; o >>= 1) sum += __shfl_xor(sum, o);
    if (lane == 0) { msh[t] = m; lsh[t] = sum; }
  }
  __syncthreads();

  // partial out
  float* pb = part + (size_t)(bh * NCH + ch) * PSTRIDE;
  for (int idx = tid; idx < TT * HD; idx += 256) {
    const int t = idx / HD, d = idx % HD;
    float acc = 0.f;
    if (ch == 0) {
      const short* vs = v_s + (size_t)(b * TT) * DIM + h * HD + d;
#pragma unroll
      for (int k = 0; k < TT; ++k)
        acc = fmaf(sc[t][k], bf2f(vs[(size_t)k * DIM]), acc);
      const short* va = v_a + (size_t)(b * KA) * DIM + h * HD + d;
      for (int k = 0; k < KA; ++k)
        acc = fmaf(sc[t][TT + k], bf2f(va[(size_t)k * DIM]), acc);
    } else {
      const short* vt = v_t + (size_t)(b * KT + t0) * DIM + h * HD + d;
      for (int k = 0; k < nk; ++k)
        acc = fmaf(sc[t][k], bf2f(vt[(size_t)k * DIM]), acc);
    }
    pb[t * HD + d] = acc;
  }
  if (tid < TT) {
    pb[TT * HD + tid] = msh[tid];
    pb[TT * HD + TT + tid] = lsh[tid];
  }
}

// ---------------- attention combine ----------------
__global__ __launch_bounds__(256) void attn_reduce(
    const float* __restrict__ part, short* __restrict__ out)
{
  __shared__ float fac[NCH][TT], inv[TT];
  const int tid = threadIdx.x;
  const int bh = blockIdx.x, b = bh >> 3, h = bh & 7;
  const float* pb = part + (size_t)bh * NCH * PSTRIDE;
  if (tid < TT) {
    const int t = tid;
    float M = -1e30f;
#pragma unroll
    for (int c = 0; c < NCH; ++c) M = fmaxf(M, pb[c * PSTRIDE + TT * HD + t]);
    float S = 0.f;
#pragma unroll
    for (int c = 0; c < NCH; ++c) {
      const float f = expf(pb[c * PSTRIDE + TT * HD + t] - M);
      fac[c][t] = f;
      S += pb[c * PSTRIDE + TT * HD + TT + t] * f;
    }
    inv[t] = 1.f / S;
  }
  __syncthreads();
  for (int idx = tid; idx < TT * HD; idx += 256) {
    const int t = idx / HD, d = idx % HD;
    float o = 0.f;
#pragma unroll
    for (int c = 0; c < NCH; ++c) o = fmaf(pb[c * PSTRIDE + t * HD + d], fac[c][t], o);
    out[(size_t)(b * TT + t) * DIM + h * HD + d] = f2bf(o * inv[t]);
  }
}

// ---------------- layernorm: fp32 in -> bf16 out ----------------
__global__ __launch_bounds__(256) void ln_kernel(
    const float* __restrict__ y, const float* __restrict__ g,
    const float* __restrict__ beta, short* __restrict__ yn)
{
  __shared__ float s1[4], s2[4];
  const int r = blockIdx.x, tid = threadIdx.x;
  const float* row = y + (size_t)r * DIM;
  float sum = 0.f, sq = 0.f;
  for (int c = tid; c < DIM; c += 256) {
    const float v = row[c];
    sum += v;
    sq = fmaf(v, v, sq);
  }
#pragma unroll
  for (int o = 32; o >= 1; o >>= 1) {
    sum += __shfl_xor(sum, o);
    sq  += __shfl_xor(sq, o);
  }
  const int wave = tid >> 6, lane = tid & 63;
  if (lane == 0) { s1[wave] = sum; s2[wave] = sq; }
  __syncthreads();
  sum = s1[0] + s1[1] + s1[2] + s1[3];
  sq  = s2[0] + s2[1] + s2[2] + s2[3];
  const float mu = sum / DIM;
  const float var = sq / DIM - mu * mu;
  const float rstd = 1.f / sqrtf(var + 1e-5f);
  for (int c = tid; c < DIM; c += 256)
    yn[(size_t)r * DIM + c] = f2bf((row[c] - mu) * rstd * g[c] + beta[c]);
}

// ---------------- launch ----------------
extern "C" void kernel_launch(void* const* d_in, const int* in_sizes, int n_in,
                              void* d_out, int out_size, void* d_ws, size_t ws_size,
                              hipStream_t stream)
{
  const float* x   = (const float*)d_in[0];
  const float* h_a = (const float*)d_in[1];
  const float* h_t = (const float*)d_in[2];
  const float* p   = (const float*)d_in[3];
  const float* Wq  = (const float*)d_in[4];  const float* bq  = (const float*)d_in[5];
  const float* Wks = (const float*)d_in[6];  const float* bks = (const float*)d_in[7];
  const float* Wvs = (const float*)d_in[8];  const float* bvs = (const float*)d_in[9];
  const float* Wka = (const float*)d_in[10]; const float* bka = (const float*)d_in[11];
  const float* Wva = (const float*)d_in[12]; const float* bva = (const float*)d_in[13];
  const float* Wkt = (const float*)d_in[14]; const float* bkt = (const float*)d_in[15];
  const float* Wvt = (const float*)d_in[16]; const float* bvt = (const float*)d_in[17];
  const float* Wo  = (const float*)d_in[18]; const float* bo  = (const float*)d_in[19];
  const float* Wf  = (const float*)d_in[20]; const float* bf_ = (const float*)d_in[21];
  const float* gate = (const float*)d_in[22];
  const float* ln_g = (const float*)d_in[23];
  const float* ln_b = (const float*)d_in[24];

  // ---- workspace (bytes); total 161.9 MB < proven 167.7 MB ----
  const size_t SZ_HAD = (size_t)KAPAD * DIM * 2;
  const size_t SZ_SM  = (size_t)BB * TT * DIM * 2;
  const size_t SZ_T   = (size_t)BB * KT * DIM * 2;
  const size_t SZ_WT  = (size_t)9 * DD * 2;
  const size_t needed = SZ_HAD * 3 + SZ_SM * 6 + SZ_T * 2 + SZ_WT
                        + (size_t)BB * TT * DIM * 4;
  if (ws_size < needed) return;

  char* wsp = (char*)d_ws;
  short* hadb = (short*)wsp; wsp += SZ_HAD;
  short* xb   = (short*)wsp; wsp += SZ_SM;
  short* qb   = (short*)wsp; wsp += SZ_SM;
  short* ksb  = (short*)wsp; wsp += SZ_SM;
  short* vsb  = (short*)wsp; wsp += SZ_SM;
  short* kab  = (short*)wsp; wsp += SZ_HAD;
  short* vab  = (short*)wsp; wsp += SZ_HAD;
  short* ktb  = (short*)wsp; wsp += SZ_T;
  short* vtb  = (short*)wsp; wsp += SZ_T;
  short* WtA  = (short*)wsp; wsp += SZ_WT;
  short* attn_outb = (short*)wsp; wsp += SZ_SM;
  float* yb   = (float*)wsp; wsp += (size_t)BB * TT * DIM * 4;
  short* ynb  = (short*)wsp; wsp += SZ_SM;
  // attention partials (7.47 MB) alias hadb (7.57 MB) — hadb dead after A-group GEMM
  float* part = (float*)hadb;

  dim3 blk(256);

  // 0) weights -> bf16 [n][k]
  W9 w9; const float* Ws[9] = {Wq, Wks, Wvs, Wka, Wva, Wkt, Wvt, Wo, Wf};
  for (int i = 0; i < 9; ++i) w9.w[i] = Ws[i];
  wtrans<<<dim3(28, 28, 9), blk, 0, stream>>>(w9, WtA);

  // 1) small activations -> bf16
  convert_bf16<<<(BB * TT * DIM / 8 + 255) / 256, blk, 0, stream>>>(x, xb, BB * TT * DIM / 8);
  build_had<<<(KAPAD * DIM / 8 + 255) / 256, blk, 0, stream>>>(h_a, p, hadb);

  // 2) S-group: [q | k_s | v_s] = xb @ [Wq|Wks|Wvs]
  {
    EpiCfg c = {};
    c.bias[0] = bq;  c.outB[0] = qb;  c.epi[0] = EPI_ROPE; c.pos_mod[0] = TT;
    c.bias[1] = bks; c.outB[1] = ksb; c.epi[1] = EPI_ROPE; c.pos_mod[1] = TT;
    c.bias[2] = bvs; c.outB[2] = vsb; c.epi[2] = EPI_NONE; c.pos_mod[2] = 1;
    gemm_bf16<<<dim3(21, BB * TT / 128), blk, 0, stream>>>(xb, WtA, c);
  }
  // 3) A-group: [k_a | v_a] = hadb @ [Wka|Wva]
  {
    EpiCfg c = {};
    c.bias[0] = bka; c.outB[0] = kab; c.epi[0] = EPI_ROPE; c.pos_mod[0] = KA;
    c.bias[1] = bva; c.outB[1] = vab; c.epi[1] = EPI_NONE; c.pos_mod[1] = 1;
    gemm_bf16<<<dim3(14, KAPAD / 128), blk, 0, stream>>>(hadb, WtA + (size_t)3 * DD, c);
  }
  // 4) T-group, fp32 A direct: [k_t | v_t] = h_t @ [Wkt|Wvt], single dispatch
  {
    EpiCfg c = {};
    c.bias[0] = bkt; c.outB[0] = ktb; c.epi[0] = EPI_ROPE; c.pos_mod[0] = KT;
    c.bias[1] = bvt; c.outB[1] = vtb; c.epi[1] = EPI_NONE; c.pos_mod[1] = 1;
    gemm_f32a<<<dim3(14, BB * KT / 128), blk, 0, stream>>>(h_t, WtA + (size_t)5 * DD, c);
  }

  // 5) attention: split-K partials + combine
  attn_part<<<dim3(BB * NH, NCH), blk, 0, stream>>>(qb, ksb, kab, ktb, vsb, vab, vtb,
                                                    gate, part);
  attn_reduce<<<BB * NH, blk, 0, stream>>>(part, attn_outb);

  // 6) out-proj + residual, LN, FFN + ReLU
  {
    EpiCfg c = {};
    c.bias[0] = bo; c.outF[0] = yb; c.epi[0] = EPI_RESID; c.pos_mod[0] = 1;
    c.resid = x;
    gemm_bf16<<<dim3(7, BB * TT / 128), blk, 0, stream>>>(attn_outb, WtA + (size_t)7 * DD, c);
  }
  ln_kernel<<<BB * TT, blk, 0, stream>>>(yb, ln_g, ln_b, ynb);
  {
    EpiCfg c = {};
    c.bias[0] = bf_; c.outF[0] = (float*)d_out; c.epi[0] = EPI_RELU; c.pos_mod[0] = 1;
    gemm_bf16<<<dim3(7, BB * TT / 128), blk, 0, stream>>>(ynb, WtA + (size_t)8 * DD, c);
  }
}